// Round 2
// baseline (299.822 us; speedup 1.0000x reference)
//
#include <hip/hip_runtime.h>
#include <math.h>

// Pipeline (4 launches):
//  memset:   zero tcnt + bucket_count + deg (contiguous head of ws)
//  classify: split node ids by type into list0/list1 (wave-aggregated atomics)
//  proj_scatter (FUSED): one grid, branch on blockIdx.
//     - blocks [0, NSORT): bucket_scatter at 256 thr/block. Edges into per-bucket
//       slabs bdata[b*CAP..] (bucket = dst>>6, 64 dsts -> one attn block each).
//       Also accumulates global per-dst degree deg[] (removes attn's count pass).
//       chunk ~13.3K keeps ~17-edge write runs per (block,bucket) at the finer
//       bucket granularity (coalescing lesson, R6).
//     - blocks [NSORT, NSORT+PGRID): per-type register-tiled GEMM
//       z[list[i]] = A[list[i]] @ W.
//  attn_fused: one 512-thr block per bucket (64 dsts). Wave 0 scans deg -> excl,
//     ONE scatter pass builds per-dst CSR in LDS (ushort srcs), then 8 waves x
//     8 dsts online-softmax attention: 8 lanes/edge (8 edges/wave-iter, 3-shfl
//     reduce) with a 1-deep prefetch pipeline on the z[src] gather to hide L2
//     latency under the dot+softmax chain; out = elu().
// Assumes N <= 65536 (src packed into low 16 bits of bdata).

#define F 64
#define TM 128
#define TK 64
#define BSH 6                    // bucket = dst >> 6 (64 dsts per bucket)
#define NSORT 94                 // scatter blocks (256-thr); chunk ~= 13300
#define CAP 2048                 // slab capacity per bucket (mean 1600, +11 sigma)
#define HCAP 2048                // per-bucket LDS list capacity

#define PROJ_LDS (128 * (TK + 1) * 4 + TK * F * 4)   // 33280 + 16384 = 49664 B

__global__ void classify_kernel(const int* __restrict__ node_type, int* __restrict__ tcnt,
                                int* __restrict__ list0, int* __restrict__ list1, int n) {
    int i = blockIdx.x * 256 + threadIdx.x;
    if (i < n) {
        int lane = threadIdx.x & 63;
        int t = node_type[i];
        unsigned long long b1 = __ballot(t == 1);
        unsigned long long ba = __ballot(1);
        unsigned long long mlt = (1ull << lane) - 1ull;
        int r1 = __popcll(b1 & mlt);
        int r0 = __popcll(ba & ~b1 & mlt);
        int base0, base1;
        if (lane == 0) {
            base1 = atomicAdd(&tcnt[1], __popcll(b1));
            base0 = atomicAdd(&tcnt[0], __popcll(ba & ~b1));
        }
        base0 = __shfl(base0, 0, 64);
        base1 = __shfl(base1, 0, 64);
        if (t == 1) list1[base1 + r1] = i;
        else        list0[base0 + r0] = i;
    }
}

__global__ __launch_bounds__(256, 2)
void proj_scatter(const float* __restrict__ d_sim, const float* __restrict__ m_sim,
                  const float* __restrict__ W_d, const float* __restrict__ W_m,
                  const int* __restrict__ tcnt, const int* __restrict__ list0,
                  const int* __restrict__ list1, float* __restrict__ z,
                  const int* __restrict__ dst, const int* __restrict__ src,
                  int* __restrict__ bucket_count, int* __restrict__ bucket_data,
                  int* __restrict__ deg, int e, int nbuk, int chunk) {
    __shared__ __align__(16) char smem[PROJ_LDS];    // union: proj 49664B / scatter 12288B
    int bid = blockIdx.x;

    if (bid < NSORT) {
        // ---------------- bucket_scatter branch (256 threads) ----------------
        int* hist  = (int*)smem;        // [1024]
        int* bbase = hist + 1024;       // [1024]
        int* rk    = bbase + 1024;      // [1024]
        for (int i = threadIdx.x; i < nbuk; i += 256) { hist[i] = 0; rk[i] = 0; }
        __syncthreads();
        int beg = bid * chunk, end = min(e, beg + chunk);
        for (int i = beg + (int)threadIdx.x; i < end; i += 256) {
            int d = dst[i];
            atomicAdd(&hist[d >> BSH], 1);
            atomicAdd(&deg[d], 1);               // global per-dst degree (L2 atomic)
        }
        __syncthreads();
        for (int i = threadIdx.x; i < nbuk; i += 256)
            bbase[i] = hist[i] ? atomicAdd(&bucket_count[i], hist[i]) : 0;
        __syncthreads();
        for (int i = beg + (int)threadIdx.x; i < end; i += 256) {
            int d = dst[i];
            int b = d >> BSH;
            int r = atomicAdd(&rk[b], 1);
            int pos = bbase[b] + r;
            if (pos < CAP)                       // overflow guard (11-sigma event)
                bucket_data[(size_t)b * CAP + pos] = ((d & 63) << 16) | src[i];
        }
        return;
    }

    // ------------------------- proj_gemm branch --------------------------
    int pb = bid - NSORT;
    int ty = pb & 1;
    int cnt = tcnt[ty];
    int base = (pb >> 1) * TM;
    if (base >= cnt) return;
    const int*   list = ty ? list1 : list0;
    const float* A    = ty ? d_sim : m_sim;
    const float* W    = ty ? W_d   : W_m;

    float (*sA)[TK + 1] = (float (*)[TK + 1])smem;
    float (*sW)[F]      = (float (*)[F])(smem + 128 * (TK + 1) * 4);

    int rg = threadIdx.x >> 4;
    int cg = threadIdx.x & 15;

    int srow_node[8];
    #pragma unroll
    for (int j = 0; j < 8; j++) {
        int idx = (int)threadIdx.x + 256 * j;
        int li = base + (idx >> 4);
        if (li >= cnt) li = cnt - 1;
        srow_node[j] = list[li];
    }

    float acc[8][4] = {};
    for (int kc = 0; kc < 256; kc += TK) {
        __syncthreads();
        #pragma unroll
        for (int j = 0; j < 8; j++) {
            int idx = (int)threadIdx.x + 256 * j;
            int r = idx >> 4, f4 = idx & 15;
            float4 v = *(const float4*)(A + (size_t)srow_node[j] * 256 + kc + f4 * 4);
            sA[r][f4 * 4 + 0] = v.x;
            sA[r][f4 * 4 + 1] = v.y;
            sA[r][f4 * 4 + 2] = v.z;
            sA[r][f4 * 4 + 3] = v.w;
        }
        #pragma unroll
        for (int j = 0; j < 4; j++) {
            int idx = (int)threadIdx.x + 256 * j;
            int k = idx >> 4, f4 = idx & 15;
            float4 v = *(const float4*)(W + (size_t)(kc + k) * F + f4 * 4);
            *(float4*)&sW[k][f4 * 4] = v;
        }
        __syncthreads();
        #pragma unroll 4
        for (int k = 0; k < TK; k++) {
            float4 wv = *(const float4*)&sW[k][cg * 4];
            float a[8];
            #pragma unroll
            for (int i = 0; i < 8; i++) a[i] = sA[rg * 8 + i][k];
            #pragma unroll
            for (int i = 0; i < 8; i++) {
                acc[i][0] = fmaf(a[i], wv.x, acc[i][0]);
                acc[i][1] = fmaf(a[i], wv.y, acc[i][1]);
                acc[i][2] = fmaf(a[i], wv.z, acc[i][2]);
                acc[i][3] = fmaf(a[i], wv.w, acc[i][3]);
            }
        }
    }
    #pragma unroll
    for (int i = 0; i < 8; i++) {
        int li = base + rg * 8 + i;
        if (li < cnt) {
            int node = list[li];
            float4 v = {acc[i][0], acc[i][1], acc[i][2], acc[i][3]};
            *(float4*)(z + (size_t)node * F + cg * 4) = v;
        }
    }
}

__global__ __launch_bounds__(512)
void attn_fused(const float* __restrict__ z, const int* __restrict__ bucket_count,
                const int* __restrict__ bucket_data, const int* __restrict__ deg,
                float* __restrict__ out, int n) {
    __shared__ unsigned short ssrc[HCAP];
    __shared__ int excl[64], cur[64];
    int b = blockIdx.x;
    int dbase = b << BSH;
    const int* __restrict__ bd = bucket_data + (size_t)b * CAP;
    int len = min(bucket_count[b], CAP);
    int tid = threadIdx.x;

    if (tid < 64) {                   // wave 0: load degrees, shfl exclusive scan
        cur[tid] = 0;
        int d = dbase + tid;
        int v = (d < n) ? deg[d] : 0;
        int s = v;
        #pragma unroll
        for (int off = 1; off < 64; off <<= 1) {
            int t = __shfl_up(s, off, 64);
            if (tid >= off) s += t;
        }
        excl[tid] = s - v;
    }
    __syncthreads();
    // single pass: scatter srcs into LDS grouped by dst (bucket holds only our dsts)
    for (int i = tid; i < len; i += 512) {
        int v = bd[i];
        int d6 = v >> 16;
        int r = atomicAdd(&cur[d6], 1);
        int pos = excl[d6] + r;
        if (pos < HCAP) ssrc[pos] = (unsigned short)(v & 0xFFFF);
    }
    __syncthreads();

    // attention: wave wv handles dsts d6 = wv + 8k; 8 lanes per edge, 8 edges/iter
    int lane = tid & 63;
    int wv = tid >> 6;
    int g = lane >> 3, r = lane & 7;
    for (int k = 0; k < 8; k++) {
        int d6 = wv + 8 * k;
        int node = dbase + d6;
        if (node >= n) continue;
        int lbeg = excl[d6];
        int lcnt = min(cur[d6], max(0, HCAP - lbeg));
        const float4* zdp = (const float4*)(z + (size_t)node * F);
        float4 zd0 = zdp[r], zd1 = zdp[r + 8];
        float m = -3.402823466e38f, l = 0.f;
        float4 a0 = {0.f, 0.f, 0.f, 0.f}, a1 = {0.f, 0.f, 0.f, 0.f};
        if (lcnt > 0) {
            int s_c = ssrc[lbeg + min(g, lcnt - 1)];
            const float4* zp = (const float4*)(z + (size_t)s_c * F);
            float4 c0 = zp[r], c1 = zp[r + 8];     // [128B run][128B run] per group-octet
            for (int j = 0; j < lcnt; j += 8) {
                // prefetch next octet's src + z row; clamped index -> no divergence
                int s_n = ssrc[lbeg + min(j + 8 + g, lcnt - 1)];
                const float4* zq = (const float4*)(z + (size_t)s_n * F);
                float4 n0 = zq[r], n1 = zq[r + 8];
                int jj = j + g;
                float p;
                p = c0.x * zd0.x;
                p = fmaf(c0.y, zd0.y, p);
                p = fmaf(c0.z, zd0.z, p);
                p = fmaf(c0.w, zd0.w, p);
                p = fmaf(c1.x, zd1.x, p);
                p = fmaf(c1.y, zd1.y, p);
                p = fmaf(c1.z, zd1.z, p);
                p = fmaf(c1.w, zd1.w, p);
                p += __shfl_xor(p, 1, 64);
                p += __shfl_xor(p, 2, 64);
                p += __shfl_xor(p, 4, 64);
                float e = (p > 0.f) ? p : 0.2f * p;   // leaky_relu
                if (jj >= lcnt) e = -INFINITY;
                float t = __expf(-fabsf(e - m));      // single-exp online update
                bool gt = (e > m);
                float sc = gt ? t : 1.f;
                float w  = gt ? 1.f : t;
                m = gt ? e : m;
                l = fmaf(l, sc, w);
                a0.x = fmaf(a0.x, sc, w * c0.x);
                a0.y = fmaf(a0.y, sc, w * c0.y);
                a0.z = fmaf(a0.z, sc, w * c0.z);
                a0.w = fmaf(a0.w, sc, w * c0.w);
                a1.x = fmaf(a1.x, sc, w * c1.x);
                a1.y = fmaf(a1.y, sc, w * c1.y);
                a1.z = fmaf(a1.z, sc, w * c1.z);
                a1.w = fmaf(a1.w, sc, w * c1.w);
                c0 = n0; c1 = n1;
            }
        }
        // merge the 8 groups: xor 8, 16, 32
        #pragma unroll
        for (int off = 8; off <= 32; off <<= 1) {
            float om = __shfl_xor(m, off, 64);
            float ol = __shfl_xor(l, off, 64);
            float4 o0, o1;
            o0.x = __shfl_xor(a0.x, off, 64);
            o0.y = __shfl_xor(a0.y, off, 64);
            o0.z = __shfl_xor(a0.z, off, 64);
            o0.w = __shfl_xor(a0.w, off, 64);
            o1.x = __shfl_xor(a1.x, off, 64);
            o1.y = __shfl_xor(a1.y, off, 64);
            o1.z = __shfl_xor(a1.z, off, 64);
            o1.w = __shfl_xor(a1.w, off, 64);
            float t = __expf(-fabsf(m - om));
            bool gt = (om > m);
            float sc = gt ? t : 1.f;
            float so = gt ? 1.f : t;
            m = gt ? om : m;
            l = fmaf(l, sc, ol * so);
            a0.x = fmaf(a0.x, sc, o0.x * so);
            a0.y = fmaf(a0.y, sc, o0.y * so);
            a0.z = fmaf(a0.z, sc, o0.z * so);
            a0.w = fmaf(a0.w, sc, o0.w * so);
            a1.x = fmaf(a1.x, sc, o1.x * so);
            a1.y = fmaf(a1.y, sc, o1.y * so);
            a1.z = fmaf(a1.z, sc, o1.z * so);
            a1.w = fmaf(a1.w, sc, o1.w * so);
        }
        float inv = 1.f / fmaxf(l, 1e-16f);
        float4 o0, o1;
        o0.x = a0.x * inv; o0.y = a0.y * inv; o0.z = a0.z * inv; o0.w = a0.w * inv;
        o1.x = a1.x * inv; o1.y = a1.y * inv; o1.z = a1.z * inv; o1.w = a1.w * inv;
        o0.x = (o0.x > 0.f) ? o0.x : (__expf(o0.x) - 1.f);
        o0.y = (o0.y > 0.f) ? o0.y : (__expf(o0.y) - 1.f);
        o0.z = (o0.z > 0.f) ? o0.z : (__expf(o0.z) - 1.f);
        o0.w = (o0.w > 0.f) ? o0.w : (__expf(o0.w) - 1.f);
        o1.x = (o1.x > 0.f) ? o1.x : (__expf(o1.x) - 1.f);
        o1.y = (o1.y > 0.f) ? o1.y : (__expf(o1.y) - 1.f);
        o1.z = (o1.z > 0.f) ? o1.z : (__expf(o1.z) - 1.f);
        o1.w = (o1.w > 0.f) ? o1.w : (__expf(o1.w) - 1.f);
        if (g == 0) {
            float4* op = (float4*)(out + (size_t)node * F);
            op[r] = o0;
            op[r + 8] = o1;
        }
    }
}

extern "C" void kernel_launch(void* const* d_in, const int* in_sizes, int n_in,
                              void* d_out, int out_size, void* d_ws, size_t ws_size,
                              hipStream_t stream) {
    const float* d_sim     = (const float*)d_in[0];
    const float* m_sim     = (const float*)d_in[1];
    const float* W_d       = (const float*)d_in[2];
    const float* W_m       = (const float*)d_in[3];
    const int*   node_type = (const int*)d_in[4];
    const int*   src       = (const int*)d_in[5];
    const int*   dst       = (const int*)d_in[6];
    float* out = (float*)d_out;

    const int N = in_sizes[4];
    const int E = in_sizes[5];
    const int NBUK = (N + 63) >> BSH;           // 782 for N=50000 (<=1024 assumed)

    char* ws = (char*)d_ws;
    int*   tcnt   = (int*)ws;                         // 2
    int*   bcount = tcnt + 2;                         // 1024
    int*   deg    = bcount + 1024;                    // N
    int    head   = (2 + 1024 + N + 3) & ~3;          // align z to 16B
    float* z      = (float*)(ws + (size_t)head * 4);  // N*F
    int*   list0  = (int*)(z + (size_t)N * F);        // N
    int*   list1  = list0 + N;                        // N
    int*   bdata  = list1 + N;                        // NBUK*CAP

    hipMemsetAsync(tcnt, 0, (size_t)(2 + 1024 + N) * sizeof(int), stream);

    dim3 blk(256);
    classify_kernel<<<dim3((N + 255) / 256), blk, 0, stream>>>(node_type, tcnt, list0, list1, N);

    int pgrid = 2 * ((N + TM - 1) / TM);        // 782
    int chunk = (E + NSORT - 1) / NSORT;        // ~13300: keeps ~17-edge write runs
    proj_scatter<<<dim3(NSORT + pgrid), blk, 0, stream>>>(d_sim, m_sim, W_d, W_m,
                                                          tcnt, list0, list1, z,
                                                          dst, src, bcount, bdata,
                                                          deg, E, NBUK, chunk);
    attn_fused<<<dim3(NBUK), dim3(512), 0, stream>>>(z, bcount, bdata, deg, out, N);
}

// Round 3
// 246.452 us; speedup vs baseline: 1.2166x; 1.2166x over previous
//
#include <hip/hip_runtime.h>
#include <math.h>

// Pipeline (4 launches):
//  memset:   zero tcnt + bucket_count
//  classify: split node ids by type into list0/list1 (wave-aggregated atomics)
//  proj_scatter (FUSED): one grid, branch on blockIdx.
//     - blocks [0, nsort): bucket_scatter at 256 thr/block, 4 edges/thread via
//       int4 loads (chunk=4096 -> 4 serial iterations/pass). Edges into
//       per-bucket slabs bdata[b*CAP..] (bucket = dst>>6, 64 dsts -> one attn
//       block each). Slab allocation: one atomicAdd per (block,bucket).
//       R2 lesson: scatter is LATENCY-bound (HBM at 10%) -> maximize blocks+ILP,
//       ignore write-run coalescing.
//     - blocks [nsort, nsort+PGRID): per-type register-tiled GEMM
//       z[list[i]] = A[list[i]] @ W.
//  attn_fused: one 512-thr block per bucket (64 dsts). Two cheap LDS passes over
//     own slab (count -> scan -> scatter) build per-dst CSR (ushort srcs), then
//     8 waves x 8 dsts online-softmax attention: 8 lanes/edge (8 edges/wave-iter,
//     3-shfl reduce) + 1-deep prefetch on the z[src] gather; out = elu().
// Assumes N <= 65536 (src packed into low 16 bits of bdata).

#define F 64
#define TM 128
#define TK 64
#define BSH 6                    // bucket = dst >> 6 (64 dsts per bucket)
#define CHUNK 4096               // edges per scatter block (mult of 1024 for int4)
#define CAP 2048                 // slab capacity per bucket (mean 1600, +11 sigma)
#define HCAP 2048                // per-bucket LDS list capacity

#define PROJ_LDS (128 * (TK + 1) * 4 + TK * F * 4)   // 33280 + 16384 = 49664 B

__global__ void classify_kernel(const int* __restrict__ node_type, int* __restrict__ tcnt,
                                int* __restrict__ list0, int* __restrict__ list1, int n) {
    int i = blockIdx.x * 256 + threadIdx.x;
    if (i < n) {
        int lane = threadIdx.x & 63;
        int t = node_type[i];
        unsigned long long b1 = __ballot(t == 1);
        unsigned long long ba = __ballot(1);
        unsigned long long mlt = (1ull << lane) - 1ull;
        int r1 = __popcll(b1 & mlt);
        int r0 = __popcll(ba & ~b1 & mlt);
        int base0, base1;
        if (lane == 0) {
            base1 = atomicAdd(&tcnt[1], __popcll(b1));
            base0 = atomicAdd(&tcnt[0], __popcll(ba & ~b1));
        }
        base0 = __shfl(base0, 0, 64);
        base1 = __shfl(base1, 0, 64);
        if (t == 1) list1[base1 + r1] = i;
        else        list0[base0 + r0] = i;
    }
}

__global__ __launch_bounds__(256, 2)
void proj_scatter(const float* __restrict__ d_sim, const float* __restrict__ m_sim,
                  const float* __restrict__ W_d, const float* __restrict__ W_m,
                  const int* __restrict__ tcnt, const int* __restrict__ list0,
                  const int* __restrict__ list1, float* __restrict__ z,
                  const int* __restrict__ dst, const int* __restrict__ src,
                  int* __restrict__ bucket_count, int* __restrict__ bucket_data,
                  int e, int nbuk, int nsort) {
    __shared__ __align__(16) char smem[PROJ_LDS];    // union: proj 49664B / scatter 12288B
    int bid = blockIdx.x;

    if (bid < nsort) {
        // ---- bucket_scatter branch: 256 thr, 4 edges/thread via int4 ----
        int* hist  = (int*)smem;        // [1024]
        int* bbase = hist + 1024;       // [1024]
        int* rk    = bbase + 1024;      // [1024]
        for (int i = threadIdx.x; i < nbuk; i += 256) { hist[i] = 0; rk[i] = 0; }
        __syncthreads();
        int beg = bid * CHUNK, end = min(e, beg + CHUNK);
        // pass 1: histogram (fire-and-forget LDS atomics, 4 in flight)
        for (int i = beg + (int)threadIdx.x * 4; i < end; i += 1024) {
            int4 d4 = *(const int4*)(dst + i);      // beg,i mult of 4; e mult of 4
            atomicAdd(&hist[d4.x >> BSH], 1);
            atomicAdd(&hist[d4.y >> BSH], 1);
            atomicAdd(&hist[d4.z >> BSH], 1);
            atomicAdd(&hist[d4.w >> BSH], 1);
        }
        __syncthreads();
        for (int i = threadIdx.x; i < nbuk; i += 256)
            bbase[i] = hist[i] ? atomicAdd(&bucket_count[i], hist[i]) : 0;
        __syncthreads();
        // pass 2: scatter (4 independent rank atomics + 4 stores in flight)
        for (int i = beg + (int)threadIdx.x * 4; i < end; i += 1024) {
            int4 d4 = *(const int4*)(dst + i);
            int4 s4 = *(const int4*)(src + i);
            int b0 = d4.x >> BSH, b1 = d4.y >> BSH, b2 = d4.z >> BSH, b3 = d4.w >> BSH;
            int r0 = atomicAdd(&rk[b0], 1);
            int r1 = atomicAdd(&rk[b1], 1);
            int r2 = atomicAdd(&rk[b2], 1);
            int r3 = atomicAdd(&rk[b3], 1);
            int p0 = bbase[b0] + r0, p1 = bbase[b1] + r1;
            int p2 = bbase[b2] + r2, p3 = bbase[b3] + r3;
            if (p0 < CAP) bucket_data[(size_t)b0 * CAP + p0] = ((d4.x & 63) << 16) | s4.x;
            if (p1 < CAP) bucket_data[(size_t)b1 * CAP + p1] = ((d4.y & 63) << 16) | s4.y;
            if (p2 < CAP) bucket_data[(size_t)b2 * CAP + p2] = ((d4.z & 63) << 16) | s4.z;
            if (p3 < CAP) bucket_data[(size_t)b3 * CAP + p3] = ((d4.w & 63) << 16) | s4.w;
        }
        return;
    }

    // ------------------------- proj_gemm branch --------------------------
    int pb = bid - nsort;
    int ty = pb & 1;
    int cnt = tcnt[ty];
    int base = (pb >> 1) * TM;
    if (base >= cnt) return;
    const int*   list = ty ? list1 : list0;
    const float* A    = ty ? d_sim : m_sim;
    const float* W    = ty ? W_d   : W_m;

    float (*sA)[TK + 1] = (float (*)[TK + 1])smem;
    float (*sW)[F]      = (float (*)[F])(smem + 128 * (TK + 1) * 4);

    int rg = threadIdx.x >> 4;
    int cg = threadIdx.x & 15;

    int srow_node[8];
    #pragma unroll
    for (int j = 0; j < 8; j++) {
        int idx = (int)threadIdx.x + 256 * j;
        int li = base + (idx >> 4);
        if (li >= cnt) li = cnt - 1;
        srow_node[j] = list[li];
    }

    float acc[8][4] = {};
    for (int kc = 0; kc < 256; kc += TK) {
        __syncthreads();
        #pragma unroll
        for (int j = 0; j < 8; j++) {
            int idx = (int)threadIdx.x + 256 * j;
            int r = idx >> 4, f4 = idx & 15;
            float4 v = *(const float4*)(A + (size_t)srow_node[j] * 256 + kc + f4 * 4);
            sA[r][f4 * 4 + 0] = v.x;
            sA[r][f4 * 4 + 1] = v.y;
            sA[r][f4 * 4 + 2] = v.z;
            sA[r][f4 * 4 + 3] = v.w;
        }
        #pragma unroll
        for (int j = 0; j < 4; j++) {
            int idx = (int)threadIdx.x + 256 * j;
            int k = idx >> 4, f4 = idx & 15;
            float4 v = *(const float4*)(W + (size_t)(kc + k) * F + f4 * 4);
            *(float4*)&sW[k][f4 * 4] = v;
        }
        __syncthreads();
        #pragma unroll 4
        for (int k = 0; k < TK; k++) {
            float4 wv = *(const float4*)&sW[k][cg * 4];
            float a[8];
            #pragma unroll
            for (int i = 0; i < 8; i++) a[i] = sA[rg * 8 + i][k];
            #pragma unroll
            for (int i = 0; i < 8; i++) {
                acc[i][0] = fmaf(a[i], wv.x, acc[i][0]);
                acc[i][1] = fmaf(a[i], wv.y, acc[i][1]);
                acc[i][2] = fmaf(a[i], wv.z, acc[i][2]);
                acc[i][3] = fmaf(a[i], wv.w, acc[i][3]);
            }
        }
    }
    #pragma unroll
    for (int i = 0; i < 8; i++) {
        int li = base + rg * 8 + i;
        if (li < cnt) {
            int node = list[li];
            float4 v = {acc[i][0], acc[i][1], acc[i][2], acc[i][3]};
            *(float4*)(z + (size_t)node * F + cg * 4) = v;
        }
    }
}

__global__ __launch_bounds__(512)
void attn_fused(const float* __restrict__ z, const int* __restrict__ bucket_count,
                const int* __restrict__ bucket_data, float* __restrict__ out, int n) {
    __shared__ unsigned short ssrc[HCAP];
    __shared__ int cnt[64], excl[64], cur[64];
    int b = blockIdx.x;
    int dbase = b << BSH;
    const int* __restrict__ bd = bucket_data + (size_t)b * CAP;
    int len = min(bucket_count[b], CAP);
    int tid = threadIdx.x;

    if (tid < 64) { cnt[tid] = 0; cur[tid] = 0; }
    __syncthreads();
    // pass 1: per-dst counts (bucket holds only our 64 dsts)
    for (int i = tid; i < len; i += 512)
        atomicAdd(&cnt[bd[i] >> 16], 1);
    __syncthreads();
    if (tid < 64) {                   // wave 0: shfl exclusive scan of 64 counts
        int v = cnt[tid];
        int s = v;
        #pragma unroll
        for (int off = 1; off < 64; off <<= 1) {
            int t = __shfl_up(s, off, 64);
            if (tid >= off) s += t;
        }
        excl[tid] = s - v;
    }
    __syncthreads();
    // pass 2: scatter srcs into LDS grouped by dst
    for (int i = tid; i < len; i += 512) {
        int v = bd[i];
        int d6 = v >> 16;
        int r = atomicAdd(&cur[d6], 1);
        int pos = excl[d6] + r;
        if (pos < HCAP) ssrc[pos] = (unsigned short)(v & 0xFFFF);
    }
    __syncthreads();

    // attention: wave wv handles dsts d6 = wv + 8k; 8 lanes per edge, 8 edges/iter
    int lane = tid & 63;
    int wv = tid >> 6;
    int g = lane >> 3, r = lane & 7;
    for (int k = 0; k < 8; k++) {
        int d6 = wv + 8 * k;
        int node = dbase + d6;
        if (node >= n) continue;
        int lbeg = excl[d6];
        int lcnt = min(cnt[d6], max(0, HCAP - lbeg));
        const float4* zdp = (const float4*)(z + (size_t)node * F);
        float4 zd0 = zdp[r], zd1 = zdp[r + 8];
        float m = -3.402823466e38f, l = 0.f;
        float4 a0 = {0.f, 0.f, 0.f, 0.f}, a1 = {0.f, 0.f, 0.f, 0.f};
        if (lcnt > 0) {
            int s_c = ssrc[lbeg + min(g, lcnt - 1)];
            const float4* zp = (const float4*)(z + (size_t)s_c * F);
            float4 c0 = zp[r], c1 = zp[r + 8];
            for (int j = 0; j < lcnt; j += 8) {
                // prefetch next octet's src + z row; clamped index -> no divergence
                int s_n = ssrc[lbeg + min(j + 8 + g, lcnt - 1)];
                const float4* zq = (const float4*)(z + (size_t)s_n * F);
                float4 n0 = zq[r], n1 = zq[r + 8];
                int jj = j + g;
                float p;
                p = c0.x * zd0.x;
                p = fmaf(c0.y, zd0.y, p);
                p = fmaf(c0.z, zd0.z, p);
                p = fmaf(c0.w, zd0.w, p);
                p = fmaf(c1.x, zd1.x, p);
                p = fmaf(c1.y, zd1.y, p);
                p = fmaf(c1.z, zd1.z, p);
                p = fmaf(c1.w, zd1.w, p);
                p += __shfl_xor(p, 1, 64);
                p += __shfl_xor(p, 2, 64);
                p += __shfl_xor(p, 4, 64);
                float e = (p > 0.f) ? p : 0.2f * p;   // leaky_relu
                if (jj >= lcnt) e = -INFINITY;
                float t = __expf(-fabsf(e - m));      // single-exp online update
                bool gt = (e > m);
                float sc = gt ? t : 1.f;
                float w  = gt ? 1.f : t;
                m = gt ? e : m;
                l = fmaf(l, sc, w);
                a0.x = fmaf(a0.x, sc, w * c0.x);
                a0.y = fmaf(a0.y, sc, w * c0.y);
                a0.z = fmaf(a0.z, sc, w * c0.z);
                a0.w = fmaf(a0.w, sc, w * c0.w);
                a1.x = fmaf(a1.x, sc, w * c1.x);
                a1.y = fmaf(a1.y, sc, w * c1.y);
                a1.z = fmaf(a1.z, sc, w * c1.z);
                a1.w = fmaf(a1.w, sc, w * c1.w);
                c0 = n0; c1 = n1;
            }
        }
        // merge the 8 groups: xor 8, 16, 32
        #pragma unroll
        for (int off = 8; off <= 32; off <<= 1) {
            float om = __shfl_xor(m, off, 64);
            float ol = __shfl_xor(l, off, 64);
            float4 o0, o1;
            o0.x = __shfl_xor(a0.x, off, 64);
            o0.y = __shfl_xor(a0.y, off, 64);
            o0.z = __shfl_xor(a0.z, off, 64);
            o0.w = __shfl_xor(a0.w, off, 64);
            o1.x = __shfl_xor(a1.x, off, 64);
            o1.y = __shfl_xor(a1.y, off, 64);
            o1.z = __shfl_xor(a1.z, off, 64);
            o1.w = __shfl_xor(a1.w, off, 64);
            float t = __expf(-fabsf(m - om));
            bool gt = (om > m);
            float sc = gt ? t : 1.f;
            float so = gt ? 1.f : t;
            m = gt ? om : m;
            l = fmaf(l, sc, ol * so);
            a0.x = fmaf(a0.x, sc, o0.x * so);
            a0.y = fmaf(a0.y, sc, o0.y * so);
            a0.z = fmaf(a0.z, sc, o0.z * so);
            a0.w = fmaf(a0.w, sc, o0.w * so);
            a1.x = fmaf(a1.x, sc, o1.x * so);
            a1.y = fmaf(a1.y, sc, o1.y * so);
            a1.z = fmaf(a1.z, sc, o1.z * so);
            a1.w = fmaf(a1.w, sc, o1.w * so);
        }
        float inv = 1.f / fmaxf(l, 1e-16f);
        float4 o0, o1;
        o0.x = a0.x * inv; o0.y = a0.y * inv; o0.z = a0.z * inv; o0.w = a0.w * inv;
        o1.x = a1.x * inv; o1.y = a1.y * inv; o1.z = a1.z * inv; o1.w = a1.w * inv;
        o0.x = (o0.x > 0.f) ? o0.x : (__expf(o0.x) - 1.f);
        o0.y = (o0.y > 0.f) ? o0.y : (__expf(o0.y) - 1.f);
        o0.z = (o0.z > 0.f) ? o0.z : (__expf(o0.z) - 1.f);
        o0.w = (o0.w > 0.f) ? o0.w : (__expf(o0.w) - 1.f);
        o1.x = (o1.x > 0.f) ? o1.x : (__expf(o1.x) - 1.f);
        o1.y = (o1.y > 0.f) ? o1.y : (__expf(o1.y) - 1.f);
        o1.z = (o1.z > 0.f) ? o1.z : (__expf(o1.z) - 1.f);
        o1.w = (o1.w > 0.f) ? o1.w : (__expf(o1.w) - 1.f);
        if (g == 0) {
            float4* op = (float4*)(out + (size_t)node * F);
            op[r] = o0;
            op[r + 8] = o1;
        }
    }
}

extern "C" void kernel_launch(void* const* d_in, const int* in_sizes, int n_in,
                              void* d_out, int out_size, void* d_ws, size_t ws_size,
                              hipStream_t stream) {
    const float* d_sim     = (const float*)d_in[0];
    const float* m_sim     = (const float*)d_in[1];
    const float* W_d       = (const float*)d_in[2];
    const float* W_m       = (const float*)d_in[3];
    const int*   node_type = (const int*)d_in[4];
    const int*   src       = (const int*)d_in[5];
    const int*   dst       = (const int*)d_in[6];
    float* out = (float*)d_out;

    const int N = in_sizes[4];
    const int E = in_sizes[5];
    const int NBUK = (N + 63) >> BSH;           // 782 for N=50000 (<=1024 assumed)

    char* ws = (char*)d_ws;
    int*   tcnt   = (int*)ws;                         // 2
    int*   bcount = tcnt + 2;                         // 1024
    int    head   = (2 + 1024 + 3) & ~3;              // align z to 16B
    float* z      = (float*)(ws + (size_t)head * 4);  // N*F
    int*   list0  = (int*)(z + (size_t)N * F);        // N
    int*   list1  = list0 + N;                        // N
    int*   bdata  = list1 + N;                        // NBUK*CAP

    hipMemsetAsync(tcnt, 0, (size_t)(2 + 1024) * sizeof(int), stream);

    dim3 blk(256);
    classify_kernel<<<dim3((N + 255) / 256), blk, 0, stream>>>(node_type, tcnt, list0, list1, N);

    int nsort = (E + CHUNK - 1) / CHUNK;        // 306 for E=1.25M
    int pgrid = 2 * ((N + TM - 1) / TM);        // 782
    proj_scatter<<<dim3(nsort + pgrid), blk, 0, stream>>>(d_sim, m_sim, W_d, W_m,
                                                          tcnt, list0, list1, z,
                                                          dst, src, bcount, bdata,
                                                          E, NBUK, nsort);
    attn_fused<<<dim3(NBUK), dim3(512), 0, stream>>>(z, bcount, bdata, out, N);
}

// Round 5
// 242.199 us; speedup vs baseline: 1.2379x; 1.0176x over previous
//
#include <hip/hip_runtime.h>
#include <math.h>

// Pipeline (4 launches) — best-measured variant of each phase (post-R4 reset):
//  memset:   zero tcnt + bucket_count
//  classify: split node ids by type into list0/list1 (wave-aggregated atomics)
//  proj_scatter (FUSED): one grid, branch on blockIdx.
//     - blocks [0, nsort): bucket_scatter at 256 thr/block, 4 edges/thread via
//       int4 loads (chunk=4096). Edges into per-bucket slabs bdata[b*CAP..]
//       (bucket = dst>>5, 32 dsts -> one attn block each). Slab alloc: one
//       atomicAdd per (block,bucket). R2 lesson: scatter is latency-bound ->
//       maximize blocks+ILP, ignore write-run coalescing.
//     - blocks [nsort, nsort+PGRID): per-type register-tiled GEMM
//       z[list[i]] = A[list[i]] @ W.
//  attn_fused: one 512-thr block per 32-dst bucket (1563 blocks -> no tail
//     imbalance; R3's 47% occupancy was the 782-block tail). Two cheap LDS
//     passes over own slab build per-dst CSR (ushort srcs), then 8 waves x
//     4 dsts online-softmax attention with the R1-MEASURED-BEST gather
//     (16 lanes/edge, 4-shfl reduce, no prefetch — R3's 8-lane+prefetch
//     variant was 64us vs R1's 57.7us, reverted); out = elu().
// Assumes N <= 65536 (src packed into low 16 bits of bdata; NBUK <= 2048).

#define F 64
#define TM 128
#define TK 64
#define BSH 5                    // bucket = dst >> 5 (32 dsts per bucket)
#define CHUNK 4096               // edges per scatter block (mult of 4)
#define CAP 1280                 // slab capacity per bucket (mean 800, +17 sigma)
#define HCAP 1280                // per-bucket LDS list capacity

#define PROJ_LDS (128 * (TK + 1) * 4 + TK * F * 4)   // 33280 + 16384 = 49664 B

__global__ void classify_kernel(const int* __restrict__ node_type, int* __restrict__ tcnt,
                                int* __restrict__ list0, int* __restrict__ list1, int n) {
    int i = blockIdx.x * 256 + threadIdx.x;
    if (i < n) {
        int lane = threadIdx.x & 63;
        int t = node_type[i];
        unsigned long long b1 = __ballot(t == 1);
        unsigned long long ba = __ballot(1);
        unsigned long long mlt = (1ull << lane) - 1ull;
        int r1 = __popcll(b1 & mlt);
        int r0 = __popcll(ba & ~b1 & mlt);
        int base0, base1;
        if (lane == 0) {
            base1 = atomicAdd(&tcnt[1], __popcll(b1));
            base0 = atomicAdd(&tcnt[0], __popcll(ba & ~b1));
        }
        base0 = __shfl(base0, 0, 64);
        base1 = __shfl(base1, 0, 64);
        if (t == 1) list1[base1 + r1] = i;
        else        list0[base0 + r0] = i;
    }
}

__global__ __launch_bounds__(256, 2)
void proj_scatter(const float* __restrict__ d_sim, const float* __restrict__ m_sim,
                  const float* __restrict__ W_d, const float* __restrict__ W_m,
                  const int* __restrict__ tcnt, const int* __restrict__ list0,
                  const int* __restrict__ list1, float* __restrict__ z,
                  const int* __restrict__ dst, const int* __restrict__ src,
                  int* __restrict__ bucket_count, int* __restrict__ bucket_data,
                  int e, int nbuk, int nsort) {
    __shared__ __align__(16) char smem[PROJ_LDS];    // union: proj 49664B / scatter 24576B
    int bid = blockIdx.x;

    if (bid < nsort) {
        // ---- bucket_scatter branch: 256 thr, 4 edges/thread via int4 ----
        int* hist  = (int*)smem;        // [2048]
        int* bbase = hist + 2048;       // [2048]
        int* rk    = bbase + 2048;      // [2048]
        for (int i = threadIdx.x; i < nbuk; i += 256) { hist[i] = 0; rk[i] = 0; }
        __syncthreads();
        int beg = bid * CHUNK, end = min(e, beg + CHUNK);
        // pass 1: histogram (fire-and-forget LDS atomics, 4 in flight)
        for (int i = beg + (int)threadIdx.x * 4; i < end; i += 1024) {
            int4 d4 = *(const int4*)(dst + i);      // beg,i mult of 4; e mult of 4
            atomicAdd(&hist[d4.x >> BSH], 1);
            atomicAdd(&hist[d4.y >> BSH], 1);
            atomicAdd(&hist[d4.z >> BSH], 1);
            atomicAdd(&hist[d4.w >> BSH], 1);
        }
        __syncthreads();
        for (int i = threadIdx.x; i < nbuk; i += 256)
            bbase[i] = hist[i] ? atomicAdd(&bucket_count[i], hist[i]) : 0;
        __syncthreads();
        // pass 2: scatter (4 independent rank atomics + 4 stores in flight)
        for (int i = beg + (int)threadIdx.x * 4; i < end; i += 1024) {
            int4 d4 = *(const int4*)(dst + i);
            int4 s4 = *(const int4*)(src + i);
            int b0 = d4.x >> BSH, b1 = d4.y >> BSH, b2 = d4.z >> BSH, b3 = d4.w >> BSH;
            int r0 = atomicAdd(&rk[b0], 1);
            int r1 = atomicAdd(&rk[b1], 1);
            int r2 = atomicAdd(&rk[b2], 1);
            int r3 = atomicAdd(&rk[b3], 1);
            int p0 = bbase[b0] + r0, p1 = bbase[b1] + r1;
            int p2 = bbase[b2] + r2, p3 = bbase[b3] + r3;
            if (p0 < CAP) bucket_data[(size_t)b0 * CAP + p0] = ((d4.x & 31) << 16) | s4.x;
            if (p1 < CAP) bucket_data[(size_t)b1 * CAP + p1] = ((d4.y & 31) << 16) | s4.y;
            if (p2 < CAP) bucket_data[(size_t)b2 * CAP + p2] = ((d4.z & 31) << 16) | s4.z;
            if (p3 < CAP) bucket_data[(size_t)b3 * CAP + p3] = ((d4.w & 31) << 16) | s4.w;
        }
        return;
    }

    // ------------------------- proj_gemm branch --------------------------
    int pb = bid - nsort;
    int ty = pb & 1;
    int cnt = tcnt[ty];
    int base = (pb >> 1) * TM;
    if (base >= cnt) return;
    const int*   list = ty ? list1 : list0;
    const float* A    = ty ? d_sim : m_sim;
    const float* W    = ty ? W_d   : W_m;

    float (*sA)[TK + 1] = (float (*)[TK + 1])smem;
    float (*sW)[F]      = (float (*)[F])(smem + 128 * (TK + 1) * 4);

    int rg = threadIdx.x >> 4;
    int cg = threadIdx.x & 15;

    int srow_node[8];
    #pragma unroll
    for (int j = 0; j < 8; j++) {
        int idx = (int)threadIdx.x + 256 * j;
        int li = base + (idx >> 4);
        if (li >= cnt) li = cnt - 1;
        srow_node[j] = list[li];
    }

    float acc[8][4] = {};
    for (int kc = 0; kc < 256; kc += TK) {
        __syncthreads();
        #pragma unroll
        for (int j = 0; j < 8; j++) {
            int idx = (int)threadIdx.x + 256 * j;
            int r = idx >> 4, f4 = idx & 15;
            float4 v = *(const float4*)(A + (size_t)srow_node[j] * 256 + kc + f4 * 4);
            sA[r][f4 * 4 + 0] = v.x;
            sA[r][f4 * 4 + 1] = v.y;
            sA[r][f4 * 4 + 2] = v.z;
            sA[r][f4 * 4 + 3] = v.w;
        }
        #pragma unroll
        for (int j = 0; j < 4; j++) {
            int idx = (int)threadIdx.x + 256 * j;
            int k = idx >> 4, f4 = idx & 15;
            float4 v = *(const float4*)(W + (size_t)(kc + k) * F + f4 * 4);
            *(float4*)&sW[k][f4 * 4] = v;
        }
        __syncthreads();
        #pragma unroll 4
        for (int k = 0; k < TK; k++) {
            float4 wv = *(const float4*)&sW[k][cg * 4];
            float a[8];
            #pragma unroll
            for (int i = 0; i < 8; i++) a[i] = sA[rg * 8 + i][k];
            #pragma unroll
            for (int i = 0; i < 8; i++) {
                acc[i][0] = fmaf(a[i], wv.x, acc[i][0]);
                acc[i][1] = fmaf(a[i], wv.y, acc[i][1]);
                acc[i][2] = fmaf(a[i], wv.z, acc[i][2]);
                acc[i][3] = fmaf(a[i], wv.w, acc[i][3]);
            }
        }
    }
    #pragma unroll
    for (int i = 0; i < 8; i++) {
        int li = base + rg * 8 + i;
        if (li < cnt) {
            int node = list[li];
            float4 v = {acc[i][0], acc[i][1], acc[i][2], acc[i][3]};
            *(float4*)(z + (size_t)node * F + cg * 4) = v;
        }
    }
}

__global__ __launch_bounds__(512)
void attn_fused(const float* __restrict__ z, const int* __restrict__ bucket_count,
                const int* __restrict__ bucket_data, float* __restrict__ out, int n) {
    __shared__ unsigned short ssrc[HCAP];
    __shared__ int cnt[32], excl[32], cur[32];
    int b = blockIdx.x;
    int dbase = b << BSH;
    const int* __restrict__ bd = bucket_data + (size_t)b * CAP;
    int len = min(bucket_count[b], CAP);
    int tid = threadIdx.x;

    if (tid < 32) { cnt[tid] = 0; cur[tid] = 0; }
    __syncthreads();
    // pass 1: per-dst counts (bucket holds only our 32 dsts)
    for (int i = tid; i < len; i += 512)
        atomicAdd(&cnt[bd[i] >> 16], 1);
    __syncthreads();
    if (tid < 32) {                   // 32-wide shfl exclusive scan (one wave)
        int v = cnt[tid];
        int s = v;
        #pragma unroll
        for (int off = 1; off < 32; off <<= 1) {
            int t = __shfl_up(s, off, 32);
            if (tid >= off) s += t;
        }
        excl[tid] = s - v;
    }
    __syncthreads();
    // pass 2: scatter srcs into LDS grouped by dst
    for (int i = tid; i < len; i += 512) {
        int v = bd[i];
        int d5 = v >> 16;
        int r = atomicAdd(&cur[d5], 1);
        int pos = excl[d5] + r;
        if (pos < HCAP) ssrc[pos] = (unsigned short)(v & 0xFFFF);
    }
    __syncthreads();

    // attention: wave wv handles dsts d5 = wv + 8k; 16 lanes/edge (R1-best)
    int lane = tid & 63;
    int wv = tid >> 6;
    int g = lane >> 4, r = lane & 15;
    for (int k = 0; k < 4; k++) {
        int d5 = wv + 8 * k;
        int node = dbase + d5;
        if (node >= n) continue;
        int lbeg = excl[d5];
        int lcnt = min(cnt[d5], max(0, HCAP - lbeg));
        float4 zd = ((const float4*)(z + (size_t)node * F))[r];
        float m = -3.402823466e38f, l = 0.f;
        float4 acc = {0.f, 0.f, 0.f, 0.f};
        for (int j = 0; j < lcnt; j += 4) {
            int jj = j + g;
            int s = ssrc[lbeg + min(jj, lcnt - 1)];   // LDS broadcast per group
            float4 zc = ((const float4*)(z + (size_t)s * F))[r];
            float p = fmaf(zc.x, zd.x, fmaf(zc.y, zd.y, fmaf(zc.z, zd.z, zc.w * zd.w)));
            p += __shfl_xor(p, 1, 64);
            p += __shfl_xor(p, 2, 64);
            p += __shfl_xor(p, 4, 64);
            p += __shfl_xor(p, 8, 64);
            float e = (p > 0.f) ? p : 0.2f * p;       // leaky_relu
            if (jj >= lcnt) e = -INFINITY;
            float t = __expf(-fabsf(e - m));          // single-exp online update
            bool gt = (e > m);
            float sc = gt ? t : 1.f;
            float w  = gt ? 1.f : t;
            m = gt ? e : m;
            l = fmaf(l, sc, w);
            acc.x = fmaf(acc.x, sc, w * zc.x);
            acc.y = fmaf(acc.y, sc, w * zc.y);
            acc.z = fmaf(acc.z, sc, w * zc.z);
            acc.w = fmaf(acc.w, sc, w * zc.w);
        }
        // merge the 4 groups
        #pragma unroll
        for (int off = 16; off <= 32; off <<= 1) {
            float om = __shfl_xor(m, off, 64);
            float ol = __shfl_xor(l, off, 64);
            float4 oa;
            oa.x = __shfl_xor(acc.x, off, 64);
            oa.y = __shfl_xor(acc.y, off, 64);
            oa.z = __shfl_xor(acc.z, off, 64);
            oa.w = __shfl_xor(acc.w, off, 64);
            float t = __expf(-fabsf(m - om));
            bool gt = (om > m);
            float sc = gt ? t : 1.f;
            float so = gt ? 1.f : t;
            m = gt ? om : m;
            l = fmaf(l, sc, ol * so);
            acc.x = fmaf(acc.x, sc, oa.x * so);
            acc.y = fmaf(acc.y, sc, oa.y * so);
            acc.z = fmaf(acc.z, sc, oa.z * so);
            acc.w = fmaf(acc.w, sc, oa.w * so);
        }
        float inv = 1.f / fmaxf(l, 1e-16f);
        float4 o;
        o.x = acc.x * inv; o.y = acc.y * inv; o.z = acc.z * inv; o.w = acc.w * inv;
        o.x = (o.x > 0.f) ? o.x : (__expf(o.x) - 1.f);
        o.y = (o.y > 0.f) ? o.y : (__expf(o.y) - 1.f);
        o.z = (o.z > 0.f) ? o.z : (__expf(o.z) - 1.f);
        o.w = (o.w > 0.f) ? o.w : (__expf(o.w) - 1.f);
        if (g == 0) ((float4*)(out + (size_t)node * F))[r] = o;
    }
}

extern "C" void kernel_launch(void* const* d_in, const int* in_sizes, int n_in,
                              void* d_out, int out_size, void* d_ws, size_t ws_size,
                              hipStream_t stream) {
    const float* d_sim     = (const float*)d_in[0];
    const float* m_sim     = (const float*)d_in[1];
    const float* W_d       = (const float*)d_in[2];
    const float* W_m       = (const float*)d_in[3];
    const int*   node_type = (const int*)d_in[4];
    const int*   src       = (const int*)d_in[5];
    const int*   dst       = (const int*)d_in[6];
    float* out = (float*)d_out;

    const int N = in_sizes[4];
    const int E = in_sizes[5];
    const int NBUK = (N + 31) >> BSH;           // 1563 for N=50000 (<=2048 assumed)

    char* ws = (char*)d_ws;
    int*   tcnt   = (int*)ws;                         // 2
    int*   bcount = tcnt + 2;                         // 2048
    int    head   = (2 + 2048 + 3) & ~3;              // align z to 16B
    float* z      = (float*)(ws + (size_t)head * 4);  // N*F
    int*   list0  = (int*)(z + (size_t)N * F);        // N
    int*   list1  = list0 + N;                        // N
    int*   bdata  = list1 + N;                        // NBUK*CAP

    hipMemsetAsync(tcnt, 0, (size_t)(2 + 2048) * sizeof(int), stream);

    dim3 blk(256);
    classify_kernel<<<dim3((N + 255) / 256), blk, 0, stream>>>(node_type, tcnt, list0, list1, N);

    int nsort = (E + CHUNK - 1) / CHUNK;        // 306 for E=1.25M
    int pgrid = 2 * ((N + TM - 1) / TM);        // 782
    proj_scatter<<<dim3(nsort + pgrid), blk, 0, stream>>>(d_sim, m_sim, W_d, W_m,
                                                          tcnt, list0, list1, z,
                                                          dst, src, bcount, bdata,
                                                          E, NBUK, nsort);
    attn_fused<<<dim3(NBUK), dim3(512), 0, stream>>>(z, bcount, bdata, out, N);
}